// Round 6
// baseline (1557.260 us; speedup 1.0000x reference)
//
#include <hip/hip_runtime.h>
#include <hip/hip_fp16.h>
#include <hip/hip_cooperative_groups.h>
#include <cmath>

namespace cg = cooperative_groups;

#define LNUM 6
#define DM   1152
#define DHEAD 256
#define NH   4
#define FF   6912
#define VOC  65536
#define HIST 4095
#define SEQ  4096
#define EPSV 1e-6f
#define NB   256
#define BS   1024

// ---- coop-path ws float offsets ----
#define QKV_O 0            // [6][1536]
#define AP_O  9216         // [6][1152]
#define DP_O  16128        // [6][1152]
#define GU_O  23040        // [6][13824]
#define ZEND  105984
#define HIN_O 105984       // [6][1152]
#define HM_O  112896       // [6][1152]
#define POP_O 119808       // [128][1024]
#define SPS_O 250880       // [128][4]
#define LGP_O 251392       // [8][65536]
#define AMV_O 775680       // [256]
#define AMI_O 775936       // [256]

// ---- fallback-path (round-2 verbatim) ws float offsets ----
#define F_QKV_O 0
#define F_AP_O  9216
#define F_DP_O  16128
#define F_ZEND  23040
#define F_POP_O 23040
#define F_SPS_O 154112
#define F_GUP_O 154624
#define F_LGP_O 375808
#define F_HIN_O 769024
#define F_HM_O  775936
#define F_AMV_O 782848
#define F_AMI_O 782976

struct P {
    const int* ids; const int* aflag;
    const float* kc; const float* vc;
    const int* tbl; const float* esc; const float* ezp;
    const float* w_in; const float* w_qn; const float* w_kn;
    const float* Wq; const float* Wk; const float* Wv; const float* Wo;
    const float* w_pa; const float* w_pf; const float* w_pof;
    const float* Wg; const float* Wu; const float* Wd;
    const float* w_fin; const float* Wlm;
    float* keys; float* vals; float* tok; float* ws;
};

__device__ __forceinline__ float bsum1024(float v, float* red16) {
#pragma unroll
    for (int off = 32; off; off >>= 1) v += __shfl_xor(v, off);
    if ((threadIdx.x & 63) == 0) red16[threadIdx.x >> 6] = v;
    __syncthreads();
    float r = 0.f;
#pragma unroll
    for (int i = 0; i < 16; ++i) r += red16[i];
    __syncthreads();
    return r;
}

// ==================== cooperative mega kernel: 256 blocks x 1024 threads ====================
__global__ __launch_bounds__(BS, 4) void mega(P p) {
    cg::grid_group gg = cg::this_grid();
    __shared__ float sm[7680];
    const int t = threadIdx.x, bid = blockIdx.x;
    float* ws = p.ws;

    // ---------- phase 0: zero accumulators + embed + cache copies ----------
    {
        int g = bid * BS + t;
        if (g < ZEND) ws[g] = 0.f;
        if (bid == 0) {
            int tk = p.ids[0];
            float sc = p.esc[tk], z = p.ezp[tk];
            const int* row = p.tbl + (size_t)tk * DM;
            for (int i = t; i < DM; i += BS) ws[HIN_O + i] = (float)row[i] * sc + z;
        }
        for (int rr = 0; rr < 6; ++rr) {           // keys: 1536 rows, 6/block
            int row = bid * 6 + rr;
            const float* src = p.kc + (size_t)row * HIST;
            float* dst = p.keys + (size_t)row * SEQ;
            for (int s = t; s < HIST; s += BS) dst[s] = src[s];
        }
        for (int rr = 0; rr < 6; ++rr) {           // vals: 24570 rows, 96/block, float4
            int r = bid * 96 + rr * 16 + (t >> 6);
            if (r < LNUM * HIST) {
                int l = r / HIST, sI = r - l * HIST;
                ((float4*)(p.vals + ((size_t)l * SEQ + sI) * DHEAD))[t & 63] =
                    ((const float4*)(p.vc + (size_t)r * DHEAD))[t & 63];
            }
        }
    }
    gg.sync();

    for (int l = 0; l < LNUM; ++l) {
        float* QKV = ws + QKV_O + l * 1536;
        float* AP  = ws + AP_O + l * DM;
        float* DP  = ws + DP_O + l * DM;
        float* GU  = ws + GU_O + l * 13824;
        float* HIN = ws + HIN_O + l * DM;
        float* HM  = ws + HM_O + l * DM;
        float* POP = ws + POP_O;
        float* SPS = ws + SPS_O;
        float* keys_l = p.keys + (size_t)l * DHEAD * SEQ;
        float* vals_l = p.vals + (size_t)l * SEQ * DHEAD;

        // ---------- qkv: prefix + 96 GEMV units ----------
        {
            float* xv = sm; float* red16 = sm + 1152; float* qred = sm + 1280;
            if (l == 0) {
                for (int i = t; i < DM; i += BS) xv[i] = ws[HIN_O + i];
            } else {
                const float* hprev = ws + HM_O + (l - 1) * DM;
                const float* dprev = ws + DP_O + (l - 1) * DM;
                const float* wpof = p.w_pof + (l - 1) * DM;
                float ss = 0.f;
                for (int i = t; i < DM; i += BS) { float d = dprev[i]; ss += d * d; }
                ss = bsum1024(ss, red16);
                float inv = 1.f / sqrtf(ss / DM + EPSV);
                for (int i = t; i < DM; i += BS)
                    xv[i] = hprev[i] + wpof[i] * dprev[i] * inv;
            }
            __syncthreads();
            if (bid == 0) for (int i = t; i < DM; i += BS) HIN[i] = xv[i];
            float ss = 0.f;
            for (int i = t; i < DM; i += BS) { float v = xv[i]; ss += v * v; }
            ss = bsum1024(ss, red16);
            float inv = 1.f / sqrtf(ss / DM + EPSV);
            const float* w_in = p.w_in + l * DM;
            for (int i = t; i < DM; i += BS) xv[i] = w_in[i] * xv[i] * inv;
            __syncthreads();
            if (bid < 96) {
                int cgp = bid % 6, kc = bid / 6;   // 6 col-groups x 16 k-chunks(72)
                int j = cgp * 256 + (t & 255);
                int ks = t >> 8;                    // 4 sub-slices of 18 rows
                const float* W; int jj, ncol;
                if (j < 1024)      { W = p.Wq + (size_t)l * DM * 1024; jj = j;        ncol = 1024; }
                else if (j < 1280) { W = p.Wk + (size_t)l * DM * 256;  jj = j - 1024; ncol = 256; }
                else               { W = p.Wv + (size_t)l * DM * 256;  jj = j - 1280; ncol = 256; }
                int i0 = kc * 72 + ks * 18;
                float acc = 0.f;
#pragma unroll
                for (int ii = 0; ii < 18; ++ii)
                    acc += xv[i0 + ii] * W[(size_t)(i0 + ii) * ncol + jj];
                qred[ks * 256 + (t & 255)] = acc;
                __syncthreads();
                if (ks == 0) {
                    int tj = t & 255;
                    float tot = qred[tj] + qred[256 + tj] + qred[512 + tj] + qred[768 + tj];
                    atomicAdd(&QKV[j], tot);
                }
            }
        }
        gg.sync();

        // ---------- attn (blocks 0..127, 32 positions each) ----------
        if (bid < 128) {
            float* lq  = sm;           // 1024
            float* lqf = sm + 1024;    // 1024
            float* lkn = sm + 2048;    // 256
            float* lkf = sm + 2304;    // 256
            float* lv  = sm + 2560;    // 256
            float* lp  = sm + 2816;    // 128
            float* red16 = sm + 2944;  // 16
            float* scratch = sm + 3072; // 4096 (scred then pvred)
            int s0 = bid * 32;
            bool lastb = (bid == 127);
            float base = ((l % 6) != 5) ? 1000000.f : 10000.f;
            int d = t & 255, h = t >> 8;
            int jm = d & 127;
            float theta = powf(base, -(float)(2 * jm) / 256.f);
            float ang = 4095.f * theta;
            float c = __half2float(__float2half(cosf(ang)));
            float s = __half2float(__float2half(sinf(ang)));
            lq[t] = QKV[t];
            if (t < 256) { lkn[t] = QKV[1024 + t]; lv[t] = QKV[1280 + t]; }
            __syncthreads();
            const float* wqn = p.w_qn + l * DHEAD;
            const float* wkn = p.w_kn + l * DHEAD;
            // q-norm, all 4 heads in parallel (waves never span heads)
            float v = lq[t];
            float pq = v * v;
#pragma unroll
            for (int off = 32; off; off >>= 1) pq += __shfl_xor(pq, off);
            if ((t & 63) == 0) red16[t >> 6] = pq;
            __syncthreads();
            float ssq = red16[h * 4] + red16[h * 4 + 1] + red16[h * 4 + 2] + red16[h * 4 + 3];
            float qn = wqn[d] * v / sqrtf(ssq / 256.f + EPSV);
            lq[t] = qn;
            float v2 = (t < 256) ? lkn[t] : 0.f;
            __syncthreads();             // lq(qn) visible; red16 reusable
            float pk = v2 * v2;
#pragma unroll
            for (int off = 32; off; off >>= 1) pk += __shfl_xor(pk, off);
            if ((t & 63) == 0) red16[t >> 6] = pk;
            __syncthreads();
            float ssk = red16[0] + red16[1] + red16[2] + red16[3];
            float partner = (d < 128) ? -lq[h * 256 + d + 128] : lq[h * 256 + d - 128];
            lqf[t] = qn * c + partner * s;
            float kn = 0.f;
            if (t < 256) { kn = wkn[t] * v2 / sqrtf(ssk / 256.f + EPSV); lkn[t] = kn; }
            __syncthreads();
            if (t < 256) {
                float pk2 = (t < 128) ? -lkn[t + 128] : lkn[t - 128];
                lkf[t] = kn * c + pk2 * s;
            }
            __syncthreads();
            if (lastb && t < 256) {
                keys_l[(size_t)t * SEQ + (SEQ - 1)] = lkf[t];
                vals_l[(size_t)(SEQ - 1) * DHEAD + t] = lv[t];
            }
            // scores: sl=s (32), dc=d-chunk (32 x 8)
            int sl = t & 31, dc = t >> 5;
            int sg = s0 + sl;
            bool self = lastb && (sl == 31);
            float a0 = 0, a1 = 0, a2 = 0, a3 = 0;
#pragma unroll
            for (int dd = 0; dd < 8; ++dd) {
                int dI = dc * 8 + dd;
                float kv = self ? lkf[dI] : keys_l[(size_t)dI * SEQ + sg];
                a0 += lqf[dI] * kv; a1 += lqf[256 + dI] * kv;
                a2 += lqf[512 + dI] * kv; a3 += lqf[768 + dI] * kv;
            }
            scratch[dc * 128 + sl]      = a0;
            scratch[dc * 128 + 32 + sl] = a1;
            scratch[dc * 128 + 64 + sl] = a2;
            scratch[dc * 128 + 96 + sl] = a3;
            __syncthreads();
            if (t < 128) {
                int hh = t >> 5, si = t & 31;
                int af = p.aflag[0];
                float mk = (s0 + si > 0) ? -128.f * (float)af : 0.f;
                float sc_ = 0.f;
#pragma unroll
                for (int d8 = 0; d8 < 32; ++d8) sc_ += scratch[d8 * 128 + hh * 32 + si];
                lp[hh * 32 + si] = expf(sc_ + mk);
            }
            __syncthreads();
            if (t < NH) {
                float su = 0.f;
                for (int i = 0; i < 32; ++i) su += lp[t * 32 + i];
                SPS[bid * NH + t] = su;
            }
            // PV: f4 (64) x head (4) x s-group (4 of 8)
            int f4 = t & 63, hp = (t >> 6) & 3, sr = t >> 8;
            const float4* V4 = (const float4*)vals_l;
            float4 acc = {0, 0, 0, 0};
#pragma unroll
            for (int ss_ = 0; ss_ < 8; ++ss_) {
                int sI = sr * 8 + ss_;
                float4 vv = (lastb && sI == 31) ? ((float4*)lv)[f4]
                                                : V4[(size_t)(s0 + sI) * 64 + f4];
                float pp = lp[hp * 32 + sI];
                acc.x += pp * vv.x; acc.y += pp * vv.y; acc.z += pp * vv.z; acc.w += pp * vv.w;
            }
            ((float4*)scratch)[sr * 256 + hp * 64 + f4] = acc;
            __syncthreads();
            POP[(size_t)bid * 1024 + t] =
                scratch[t] + scratch[1024 + t] + scratch[2048 + t] + scratch[3072 + t];
        }
        gg.sync();

        // ---------- wo: 72 units (9 col-groups x 8 k-chunks) ----------
        if (bid < 72) {
            float* xw = sm;            // 1024
            float* hinv = sm + 1024;   // 4
            float* red16 = sm + 1040;  // 16
            float* wored = sm + 1088;  // 1024
            for (int h2 = 0; h2 < NH; ++h2) {
                float v = (t < 128) ? SPS[t * NH + h2] : 0.f;
                float tot = bsum1024(v, red16);
                if (t == 0) hinv[h2] = 1.f / tot;
            }
            __syncthreads();
            float a = 0.f;
#pragma unroll 8
            for (int b = 0; b < 128; ++b) a += POP[(size_t)b * 1024 + t];
            xw[t] = a * hinv[t >> 8];
            __syncthreads();
            int cgp = bid % 9, kc = bid / 9;
            int col = cgp * 128 + (t & 127), kr = t >> 7;
            const float* Wo_l = p.Wo + (size_t)l * 1024 * DM;
            int ib = kc * 128 + kr * 16;
            float acc = 0.f;
#pragma unroll
            for (int r = 0; r < 16; ++r)
                acc += xw[ib + r] * Wo_l[(size_t)(ib + r) * DM + col];
            wored[kr * 128 + (t & 127)] = acc;
            __syncthreads();
            if (t < 128) {
                float tot = 0.f;
#pragma unroll
                for (int k2 = 0; k2 < 8; ++k2) tot += wored[k2 * 128 + t];
                atomicAdd(&AP[cgp * 128 + t], tot);
            }
        }
        gg.sync();

        // ---------- gu: prefix + 324 units ----------
        {
            float* xv = sm; float* red16 = sm + 1152;
            float4* gred = (float4*)(sm + 2048);   // 1024 f4
            float ss = 0.f;
            for (int i = t; i < DM; i += BS) { float a2 = AP[i]; ss += a2 * a2; }
            ss = bsum1024(ss, red16);
            float inv = 1.f / sqrtf(ss / DM + EPSV);
            const float* wpa = p.w_pa + l * DM;
            for (int i = t; i < DM; i += BS) xv[i] = HIN[i] + wpa[i] * AP[i] * inv;
            __syncthreads();
            if (bid == 0) for (int i = t; i < DM; i += BS) HM[i] = xv[i];
            float s2 = 0.f;
            for (int i = t; i < DM; i += BS) { float v = xv[i]; s2 += v * v; }
            s2 = bsum1024(s2, red16);
            float inv2 = 1.f / sqrtf(s2 / DM + EPSV);
            const float* wpf = p.w_pf + l * DM;
            for (int i = t; i < DM; i += BS) xv[i] = wpf[i] * xv[i] * inv2;
            __syncthreads();
            int f4c = t & 63, ks = t >> 6;   // 16 k-slices of 12 rows
            for (int u = bid; u < 324; u += NB) {
                int cgi = u % 54, kc = u / 54;
                bool isU = cgi >= 27;
                int cgp = isU ? cgi - 27 : cgi;
                const float4* W4 = (const float4*)((isU ? p.Wu : p.Wg) + (size_t)l * DM * FF);
                int colf = cgp * 64 + f4c;
                int i0 = kc * 192 + ks * 12;
                float4 acc = {0, 0, 0, 0};
#pragma unroll
                for (int r = 0; r < 12; ++r) {
                    float xs = xv[i0 + r];
                    float4 w = W4[(size_t)(i0 + r) * 1728 + colf];
                    acc.x += xs * w.x; acc.y += xs * w.y; acc.z += xs * w.z; acc.w += xs * w.w;
                }
                gred[ks * 64 + f4c] = acc;
                __syncthreads();
                if (t < 64) {
                    float sx = 0, sy = 0, sz = 0, sw = 0;
#pragma unroll
                    for (int k2 = 0; k2 < 16; ++k2) {
                        float4 rr = gred[k2 * 64 + t];
                        sx += rr.x; sy += rr.y; sz += rr.z; sw += rr.w;
                    }
                    float* dst = GU + (isU ? FF : 0) + (cgp * 64 + t) * 4;
                    atomicAdd(dst + 0, sx); atomicAdd(dst + 1, sy);
                    atomicAdd(dst + 2, sz); atomicAdd(dst + 3, sw);
                }
                __syncthreads();
            }
        }
        gg.sync();

        // ---------- wd: 162 units (9 col-groups x 18 k-chunks of 384) ----------
        {
            float* m = sm;                       // 384
            float4* wred = (float4*)(sm + 512);  // 1024 f4
            const float4* Wd4 = (const float4*)(p.Wd + (size_t)l * FF * DM);
            for (int u = bid; u < 162; u += NB) {
                int cgp = u % 9, kc = u / 9;
                int i0 = kc * 384;
                if (t < 384) {
                    float g = GU[i0 + t], uu = GU[FF + i0 + t];
                    float gl = 0.5f * g * (1.f + tanhf(0.7978845608028654f * (g + 0.044715f * g * g * g)));
                    m[t] = gl * uu;
                }
                __syncthreads();
                int f4c = t & 31, ks = t >> 5;   // 32 k-slices of 12 rows
                int col4 = cgp * 32 + f4c;
                float4 acc = {0, 0, 0, 0};
#pragma unroll
                for (int r = 0; r < 12; ++r) {
                    float xs = m[ks * 12 + r];
                    float4 w = Wd4[(size_t)(i0 + ks * 12 + r) * 288 + col4];
                    acc.x += xs * w.x; acc.y += xs * w.y; acc.z += xs * w.z; acc.w += xs * w.w;
                }
                wred[ks * 32 + f4c] = acc;
                __syncthreads();
                if (t < 32) {
                    float sx = 0, sy = 0, sz = 0, sw = 0;
#pragma unroll
                    for (int k2 = 0; k2 < 32; ++k2) {
                        float4 rr = wred[k2 * 32 + t];
                        sx += rr.x; sy += rr.y; sz += rr.z; sw += rr.w;
                    }
                    float* dst = DP + cgp * 128 + t * 4;
                    atomicAdd(dst + 0, sx); atomicAdd(dst + 1, sy);
                    atomicAdd(dst + 2, sz); atomicAdd(dst + 3, sw);
                }
                __syncthreads();
            }
        }
        gg.sync();
    }

    // ---------- logits: prefix + 512 units (64 col-groups x 8 k-chunks) ----------
    {
        float* xv = sm; float* red16 = sm + 1152;
        float4* lred = (float4*)(sm + 2048);   // 1024 f4
        const float* DP5 = ws + DP_O + 5 * DM;
        const float* HM5 = ws + HM_O + 5 * DM;
        const float* wpof5 = p.w_pof + 5 * DM;
        float ss = 0.f;
        for (int i = t; i < DM; i += BS) { float d = DP5[i]; ss += d * d; }
        ss = bsum1024(ss, red16);
        float inv = 1.f / sqrtf(ss / DM + EPSV);
        for (int i = t; i < DM; i += BS) xv[i] = HM5[i] + wpof5[i] * DP5[i] * inv;
        __syncthreads();
        float s2 = 0.f;
        for (int i = t; i < DM; i += BS) { float v = xv[i]; s2 += v * v; }
        s2 = bsum1024(s2, red16);
        float inv2 = 1.f / sqrtf(s2 / DM + EPSV);
        for (int i = t; i < DM; i += BS) xv[i] = p.w_fin[i] * xv[i] * inv2;
        __syncthreads();
        const float4* Wl4 = (const float4*)p.Wlm;
        int c256 = t & 255, ks = t >> 8;   // 4 k-slices of 36 rows
        for (int u = bid; u < 512; u += NB) {
            int cgp = u & 63, kc = u >> 6;
            int colf = cgp * 256 + c256;
            int i0 = kc * 144 + ks * 36;
            float4 acc = {0, 0, 0, 0};
#pragma unroll 4
            for (int r = 0; r < 36; ++r) {
                float xs = xv[i0 + r];
                float4 w = Wl4[(size_t)(i0 + r) * 16384 + colf];
                acc.x += xs * w.x; acc.y += xs * w.y; acc.z += xs * w.z; acc.w += xs * w.w;
            }
            lred[ks * 256 + c256] = acc;
            __syncthreads();
            if (ks == 0) {
                float4 r0 = lred[c256], r1 = lred[256 + c256],
                       r2 = lred[512 + c256], r3 = lred[768 + c256];
                float4 tot = {r0.x + r1.x + r2.x + r3.x, r0.y + r1.y + r2.y + r3.y,
                              r0.z + r1.z + r2.z + r3.z, r0.w + r1.w + r2.w + r3.w};
                ((float4*)(ws + LGP_O + (size_t)kc * VOC))[colf] = tot;
            }
            __syncthreads();
        }
    }
    gg.sync();

    // ---------- argmax stage 1: 256 blocks x 256 cols ----------
    {
        float* rv = sm; float* ri = sm + 256;
        if (t < 256) {
            int c = bid * 256 + t;
            float v = 0.f;
#pragma unroll
            for (int k2 = 0; k2 < 8; ++k2) v += ws[LGP_O + (size_t)k2 * VOC + c];
            rv[t] = v; ri[t] = (float)c;
        }
        __syncthreads();
        for (int off = 128; off; off >>= 1) {
            if (t < off) {
                float ov = rv[t + off], oi = ri[t + off];
                if (ov > rv[t] || (ov == rv[t] && oi < ri[t])) { rv[t] = ov; ri[t] = oi; }
            }
            __syncthreads();
        }
        if (t == 0) { ws[AMV_O + bid] = rv[0]; ws[AMI_O + bid] = ri[0]; }
    }
    gg.sync();

    // ---------- argmax stage 2 ----------
    if (bid == 0) {
        float* rv = sm; float* ri = sm + 256;
        if (t < 256) { rv[t] = ws[AMV_O + t]; ri[t] = ws[AMI_O + t]; }
        __syncthreads();
        for (int off = 128; off; off >>= 1) {
            if (t < off) {
                float ov = rv[t + off], oi = ri[t + off];
                if (ov > rv[t] || (ov == rv[t] && oi < ri[t])) { rv[t] = ov; ri[t] = oi; }
            }
            __syncthreads();
        }
        if (t == 0) p.tok[0] = ri[0];
    }
}

// ==================== fallback kernels (round-2 verbatim, known-PASS) ====================
__device__ __forceinline__ float block_sum256(float v, float* red4) {
#pragma unroll
    for (int off = 32; off; off >>= 1) v += __shfl_xor(v, off);
    int t = threadIdx.x;
    if ((t & 63) == 0) red4[t >> 6] = v;
    __syncthreads();
    float r = red4[0] + red4[1] + red4[2] + red4[3];
    __syncthreads();
    return r;
}

__global__ __launch_bounds__(256) void gk_copy(const float* __restrict__ kc,
                                               const float* __restrict__ vc,
                                               float* __restrict__ keys,
                                               float* __restrict__ vals) {
    int b = blockIdx.x;
    if (b < 24576) {
        int row = b >> 4;
        int s = ((b & 15) << 8) + threadIdx.x;
        if (s < HIST) keys[(size_t)row * SEQ + s] = kc[(size_t)row * HIST + s];
    } else {
        int r = (b - 24576) * 4 + (threadIdx.x >> 6);
        int d4 = threadIdx.x & 63;
        if (r < LNUM * HIST) {
            int l = r / HIST, sI = r - l * HIST;
            ((float4*)(vals + ((size_t)l * SEQ + sI) * DHEAD))[d4] =
                ((const float4*)(vc + (size_t)r * DHEAD))[d4];
        }
    }
}

__global__ __launch_bounds__(256) void gk_qkv(
    const float* __restrict__ Wq, const float* __restrict__ Wk, const float* __restrict__ Wv,
    const float* __restrict__ w_in, const float* __restrict__ w_pof_prev,
    const float* __restrict__ hprev, const float* __restrict__ dprev,
    const int* __restrict__ ids, const int* __restrict__ tbl,
    const float* __restrict__ escale, const float* __restrict__ ezp,
    float* __restrict__ hin_out, float* __restrict__ qkv_out, int has_prev) {
    __shared__ float xv[DM];
    __shared__ float red4[4];
    int t = threadIdx.x;
    if (has_prev) {
        float ss = 0.f;
        for (int i = t; i < DM; i += 256) { float d = dprev[i]; ss += d * d; }
        ss = block_sum256(ss, red4);
        float inv = 1.f / sqrtf(ss / DM + EPSV);
        for (int i = t; i < DM; i += 256)
            xv[i] = hprev[i] + w_pof_prev[i] * dprev[i] * inv;
    } else {
        int tok = ids[0];
        float sc = escale[tok], z = ezp[tok];
        const int* row = tbl + (size_t)tok * DM;
        for (int i = t; i < DM; i += 256) xv[i] = (float)row[i] * sc + z;
    }
    __syncthreads();
    if (blockIdx.x == 0 && blockIdx.y == 0)
        for (int i = t; i < DM; i += 256) hin_out[i] = xv[i];
    float ss = 0.f;
    for (int i = t; i < DM; i += 256) { float v = xv[i]; ss += v * v; }
    ss = block_sum256(ss, red4);
    float inv = 1.f / sqrtf(ss / DM + EPSV);
    for (int i = t; i < DM; i += 256) xv[i] = w_in[i] * xv[i] * inv;
    __syncthreads();

    int j = blockIdx.x * 256 + t;
    const float* W; int jj, ncol;
    if (j < 1024)      { W = Wq; jj = j;        ncol = 1024; }
    else if (j < 1280) { W = Wk; jj = j - 1024; ncol = 256; }
    else               { W = Wv; jj = j - 1280; ncol = 256; }
    int i0 = blockIdx.y * 36;
    float acc = 0.f;
#pragma unroll 4
    for (int ii = 0; ii < 36; ++ii)
        acc += xv[i0 + ii] * W[(size_t)(i0 + ii) * ncol + jj];
    atomicAdd(&qkv_out[j], acc);
}

__global__ __launch_bounds__(256) void gk_attn(
    const float* __restrict__ qkv, const float* __restrict__ w_qn,
    const float* __restrict__ w_kn, const int* __restrict__ attn_flag,
    float* __restrict__ keys_l, float* __restrict__ vals_l,
    float* __restrict__ po_part, float* __restrict__ sum_part, float rope_base) {
    __shared__ float lq[NH * DHEAD];
    __shared__ float lqf[NH * DHEAD];
    __shared__ float lkn[DHEAD];
    __shared__ float lkf[DHEAD];
    __shared__ float lv[DHEAD];
    __shared__ float lp[NH * 32];
    __shared__ float red4[4];
    int t = threadIdx.x;
    int s0 = blockIdx.x * 32;
    bool last = (blockIdx.x == gridDim.x - 1);

    int jm = t & 127;
    float theta = powf(rope_base, -(float)(2 * jm) / 256.f);
    float ang = 4095.f * theta;
    float c = __half2float(__float2half(cosf(ang)));
    float s = __half2float(__float2half(sinf(ang)));

    for (int h = 0; h < NH; ++h) lq[h * 256 + t] = qkv[h * 256 + t];
    lkn[t] = qkv[1024 + t];
    lv[t]  = qkv[1280 + t];
    __syncthreads();
    for (int h = 0; h < NH; ++h) {
        float v = lq[h * 256 + t];
        float ss = block_sum256(v * v, red4);
        float inv = 1.f / sqrtf(ss / 256.f + EPSV);
        float qn = w_qn[t] * v * inv;
        lq[h * 256 + t] = qn;
        __syncthreads();
        float partner = (t < 128) ? -lq[h * 256 + t + 128] : lq[h * 256 + t - 128];
        lqf[h * 256 + t] = qn * c + partner * s;
    }
    {
        float v = lkn[t];
        float ss = block_sum256(v * v, red4);
        float inv = 1.f / sqrtf(ss / 256.f + EPSV);
        float kn = w_kn[t] * v * inv;
        lkn[t] = kn;
        __syncthreads();
        float partner = (t < 128) ? -lkn[t + 128] : lkn[t - 128];
        lkf[t] = kn * c + partner * s;
    }
    __syncthreads();
    if (last) {
        keys_l[(size_t)t * SEQ + (SEQ - 1)] = lkf[t];
        vals_l[(size_t)(SEQ - 1) * DHEAD + t] = lv[t];
    }
    int sl = t & 31, dc = t >> 5;
    int sg = s0 + sl;
    bool self = last && (sl == 31);
    float a0 = 0, a1 = 0, a2 = 0, a3 = 0;
#pragma unroll 4
    for (int dd = 0; dd < 32; ++dd) {
        int d = dc * 32 + dd;
        float kv = self ? lkf[d] : keys_l[(size_t)d * SEQ + sg];
        a0 += lqf[0 * 256 + d] * kv;
        a1 += lqf[1 * 256 + d] * kv;
        a2 += lqf[2 * 256 + d] * kv;
        a3 += lqf[3 * 256 + d] * kv;
    }
    __syncthreads();
    lq[0 * 256 + t] = a0; lq[1 * 256 + t] = a1; lq[2 * 256 + t] = a2; lq[3 * 256 + t] = a3;
    __syncthreads();
    if (t < 32) {
        int af = attn_flag[0];
        float mk = (s0 + t > 0) ? -128.f * (float)af : 0.f;
        for (int h = 0; h < NH; ++h) {
            float sc_ = 0.f;
#pragma unroll
            for (int d8 = 0; d8 < 8; ++d8) sc_ += lq[h * 256 + d8 * 32 + t];
            lp[h * 32 + t] = expf(sc_ + mk);
        }
    }
    __syncthreads();
    if (t < NH) {
        float su = 0.f;
        for (int i = 0; i < 32; ++i) su += lp[t * 32 + i];
        sum_part[blockIdx.x * NH + t] = su;
    }
    float p0 = 0, p1 = 0, p2 = 0, p3 = 0;
#pragma unroll 4
    for (int ss_ = 0; ss_ < 32; ++ss_) {
        float v = (last && ss_ == 31) ? lv[t] : vals_l[(size_t)(s0 + ss_) * DHEAD + t];
        p0 += lp[0 * 32 + ss_] * v;
        p1 += lp[1 * 32 + ss_] * v;
        p2 += lp[2 * 32 + ss_] * v;
        p3 += lp[3 * 32 + ss_] * v;
    }
    float* po = po_part + (size_t)blockIdx.x * NH * DHEAD;
    po[0 * 256 + t] = p0; po[1 * 256 + t] = p1; po[2 * 256 + t] = p2; po[3 * 256 + t] = p3;
}

__global__ __launch_bounds__(256) void gk_wo(
    const float* __restrict__ po_part, const float* __restrict__ sum_part,
    const float* __restrict__ Wo_l, float* __restrict__ aproj) {
    __shared__ float x[64];
    __shared__ float hinv[NH];
    __shared__ float red4[4];
    int t = threadIdx.x;
    for (int h = 0; h < NH; ++h) {
        float v = (t < 128) ? sum_part[t * NH + h] : 0.f;
        float tot = block_sum256(v, red4);
        if (t == 0) hinv[h] = 1.f / tot;
    }
    __syncthreads();
    int i0 = blockIdx.y * 64;
    if (t < 64) {
        float a = 0.f;
#pragma unroll 8
        for (int b = 0; b < 128; ++b) a += po_part[(size_t)b * 1024 + i0 + t];
        x[t] = a * hinv[(i0 + t) >> 8];
    }
    __syncthreads();
    int j = blockIdx.x * 256 + t;
    if (j < DM) {
        float acc = 0.f;
#pragma unroll 4
        for (int ii = 0; ii < 64; ++ii)
            acc += x[ii] * Wo_l[(size_t)(i0 + ii) * DM + j];
        atomicAdd(&aproj[j], acc);
    }
}

__global__ __launch_bounds__(256) void gk_gu(
    const float* __restrict__ Wg_l, const float* __restrict__ Wu_l,
    const float* __restrict__ w_pa, const float* __restrict__ w_pf,
    const float* __restrict__ hin, const float* __restrict__ aproj,
    float* __restrict__ hmid_out, float* __restrict__ gup) {
    __shared__ float xv[DM];
    __shared__ float red4[4];
    int t = threadIdx.x;
    float ss = 0.f;
    for (int i = t; i < DM; i += 256) { float a = aproj[i]; ss += a * a; }
    ss = block_sum256(ss, red4);
    float inv = 1.f / sqrtf(ss / DM + EPSV);
    for (int i = t; i < DM; i += 256) xv[i] = hin[i] + w_pa[i] * aproj[i] * inv;
    __syncthreads();
    if (blockIdx.x == 0 && blockIdx.y == 0)
        for (int i = t; i < DM; i += 256) hmid_out[i] = xv[i];
    float s2 = 0.f;
    for (int i = t; i < DM; i += 256) { float v = xv[i]; s2 += v * v; }
    s2 = block_sum256(s2, red4);
    float inv2 = 1.f / sqrtf(s2 / DM + EPSV);
    for (int i = t; i < DM; i += 256) xv[i] = w_pf[i] * xv[i] * inv2;
    __syncthreads();

    int j2 = blockIdx.x * 256 + t;
    const float2* W2; int jj2; float* dst;
    if (j2 < FF / 2) { W2 = (const float2*)Wg_l; jj2 = j2;
                       dst = gup + (size_t)blockIdx.y * 2 * FF + 2 * j2; }
    else             { W2 = (const float2*)Wu_l; jj2 = j2 - FF / 2;
                       dst = gup + (size_t)blockIdx.y * 2 * FF + FF + 2 * (j2 - FF / 2); }
    int i0 = blockIdx.y * 72;
    float ax = 0.f, ay = 0.f;
#pragma unroll 4
    for (int ii = 0; ii < 72; ++ii) {
        float xs = xv[i0 + ii];
        float2 w = W2[(size_t)(i0 + ii) * (FF / 2) + jj2];
        ax += xs * w.x; ay += xs * w.y;
    }
    dst[0] = ax; dst[1] = ay;
}

__global__ __launch_bounds__(256) void gk_wd(const float* __restrict__ gup,
                                             const float* __restrict__ Wd_l,
                                             float* __restrict__ dproj) {
    __shared__ float m[108];
    int t = threadIdx.x;
    int i0 = blockIdx.y * 108;
    if (t < 108) {
        float g = 0.f, u = 0.f;
#pragma unroll
        for (int p = 0; p < 16; ++p) {
            g += gup[(size_t)p * 2 * FF + i0 + t];
            u += gup[(size_t)p * 2 * FF + FF + i0 + t];
        }
        float gl = 0.5f * g * (1.f + tanhf(0.7978845608028654f * (g + 0.044715f * g * g * g)));
        m[t] = gl * u;
    }
    __syncthreads();
    int j = blockIdx.x * 256 + t;
    if (j < DM) {
        float acc = 0.f;
#pragma unroll 4
        for (int ii = 0; ii < 108; ++ii)
            acc += m[ii] * Wd_l[(size_t)(i0 + ii) * DM + j];
        atomicAdd(&dproj[j], acc);
    }
}

__global__ __launch_bounds__(256) void gk_logits(
    const float* __restrict__ W_lm, const float* __restrict__ w_pof5,
    const float* __restrict__ w_fin, const float* __restrict__ hmid5,
    const float* __restrict__ dproj5, float* __restrict__ lgp) {
    __shared__ float xv[DM];
    __shared__ float red4[4];
    int t = threadIdx.x;
    float ss = 0.f;
    for (int i = t; i < DM; i += 256) { float d = dproj5[i]; ss += d * d; }
    ss = block_sum256(ss, red4);
    float inv = 1.f / sqrtf(ss / DM + EPSV);
    for (int i = t; i < DM; i += 256) xv[i] = hmid5[i] + w_pof5[i] * dproj5[i] * inv;
    __syncthreads();
    float s2 = 0.f;
    for (int i = t; i < DM; i += 256) { float v = xv[i]; s2 += v * v; }
    s2 = block_sum256(s2, red4);
    float inv2 = 1.f / sqrtf(s2 / DM + EPSV);
    for (int i = t; i < DM; i += 256) xv[i] = w_fin[i] * xv[i] * inv2;
    __syncthreads();

    int j2 = blockIdx.x * 256 + t;
    int i0 = blockIdx.y * 192;
    const float2* W2 = (const float2*)W_lm;
    float ax = 0.f, ay = 0.f;
#pragma unroll 4
    for (int ii = 0; ii < 192; ++ii) {
        float xs = xv[i0 + ii];
        float2 w = W2[(size_t)(i0 + ii) * (VOC / 2) + j2];
        ax += xs * w.x; ay += xs * w.y;
    }
    float* dst = lgp + (size_t)blockIdx.y * VOC + 2 * j2;
    dst[0] = ax; dst[1] = ay;
}

__global__ __launch_bounds__(256) void gk_amax1(const float* __restrict__ lgp,
                                                float* __restrict__ pv, float* __restrict__ pi) {
    __shared__ float rv[256];
    __shared__ int ri[256];
    int t = threadIdx.x;
    int c1 = blockIdx.x * 512 + t, c2 = c1 + 256;
    float v1 = 0.f, v2 = 0.f;
#pragma unroll
    for (int p = 0; p < 6; ++p) {
        v1 += lgp[(size_t)p * VOC + c1];
        v2 += lgp[(size_t)p * VOC + c2];
    }
    float bv; int bi;
    if (v1 >= v2) { bv = v1; bi = c1; } else { bv = v2; bi = c2; }
    rv[t] = bv; ri[t] = bi; __syncthreads();
    for (int off = 128; off > 0; off >>= 1) {
        if (t < off) {
            float ov = rv[t + off]; int oi = ri[t + off];
            if (ov > rv[t] || (ov == rv[t] && oi < ri[t])) { rv[t] = ov; ri[t] = oi; }
        }
        __syncthreads();
    }
    if (t == 0) { pv[blockIdx.x] = rv[0]; pi[blockIdx.x] = (float)ri[0]; }
}

__global__ __launch_bounds__(128) void gk_amax2(const float* __restrict__ pv,
                                                const float* __restrict__ pi,
                                                float* __restrict__ tok_out) {
    __shared__ float rv[128];
    __shared__ int ri[128];
    int t = threadIdx.x;
    rv[t] = pv[t]; ri[t] = (int)pi[t]; __syncthreads();
    for (int off = 64; off > 0; off >>= 1) {
        if (t < off) {
            float ov = rv[t + off]; int oi = ri[t + off];
            if (ov > rv[t] || (ov == rv[t] && oi < ri[t])) { rv[t] = ov; ri[t] = oi; }
        }
        __syncthreads();
    }
    if (t == 0) tok_out[0] = (float)ri[0];
}

// ==================== host launcher ====================
extern "C" void kernel_launch(void* const* d_in, const int* in_sizes, int n_in,
                              void* d_out, int out_size, void* d_ws, size_t ws_size,
                              hipStream_t stream) {
    P p;
    p.ids   = (const int*)d_in[0];
    p.aflag = (const int*)d_in[1];
    p.kc    = (const float*)d_in[2];
    p.vc    = (const float*)d_in[3];
    p.tbl   = (const int*)d_in[4];
    p.esc   = (const float*)d_in[5];
    p.ezp   = (const float*)d_in[6];
    p.w_in  = (const float*)d_in[7];
    p.w_qn  = (const float*)d_in[8];
    p.w_kn  = (const float*)d_in[9];
    p.Wq    = (const float*)d_in[10];
    p.Wk    = (const float*)d_in[11];
    p.Wv    = (const float*)d_in[12];
    p.Wo    = (const float*)d_in[13];
    p.w_pa  = (const float*)d_in[14];
    p.w_pf  = (const float*)d_in[15];
    p.w_pof = (const float*)d_in[16];
    p.Wg    = (const float*)d_in[17];
    p.Wu    = (const float*)d_in[18];
    p.Wd    = (const float*)d_in[19];
    p.w_fin = (const float*)d_in[20];
    p.Wlm   = (const float*)d_in[21];
    p.keys  = (float*)d_out;
    p.vals  = p.keys + (size_t)LNUM * DHEAD * SEQ;
    p.tok   = p.vals + (size_t)LNUM * SEQ * DHEAD;
    p.ws    = (float*)d_ws;
    float* ws = (float*)d_ws;

    void* args[] = { &p };
    hipError_t err = hipLaunchCooperativeKernel((void*)mega, dim3(NB), dim3(BS), args, 0, stream);

    if (err != hipSuccess) {
        // fallback: round-2 verbatim multi-kernel path
        hipMemsetAsync(ws, 0, F_ZEND * sizeof(float), stream);
        gk_copy<<<24576 + 6144, 256, 0, stream>>>(p.kc, p.vc, p.keys, p.vals);
        for (int l = 0; l < LNUM; ++l) {
            float* QKVl = ws + F_QKV_O + (size_t)l * 1536;
            float* APl  = ws + F_AP_O + (size_t)l * DM;
            float* DPl  = ws + F_DP_O + (size_t)l * DM;
            float* HINl = ws + F_HIN_O + (size_t)l * DM;
            float* HMl  = ws + F_HM_O + (size_t)l * DM;
            float* keys_l = p.keys + (size_t)l * DHEAD * SEQ;
            float* vals_l = p.vals + (size_t)l * SEQ * DHEAD;

            gk_qkv<<<dim3(6, 32), 256, 0, stream>>>(
                p.Wq + (size_t)l * DM * 1024, p.Wk + (size_t)l * DM * 256,
                p.Wv + (size_t)l * DM * 256, p.w_in + (size_t)l * DM,
                p.w_pof + (size_t)(l ? l - 1 : 0) * DM,
                (l ? ws + F_HM_O + (size_t)(l - 1) * DM : nullptr),
                (l ? ws + F_DP_O + (size_t)(l - 1) * DM : nullptr),
                p.ids, p.tbl, p.esc, p.ezp,
                HINl, QKVl, (l > 0) ? 1 : 0);

            gk_attn<<<128, 256, 0, stream>>>(
                QKVl, p.w_qn + (size_t)l * DHEAD, p.w_kn + (size_t)l * DHEAD,
                p.aflag, keys_l, vals_l, ws + F_POP_O, ws + F_SPS_O,
                ((l % 6) != 5) ? 1000000.0f : 10000.0f);

            gk_wo<<<dim3(5, 16), 256, 0, stream>>>(
                ws + F_POP_O, ws + F_SPS_O, p.Wo + (size_t)l * 1024 * DM, APl);

            gk_gu<<<dim3(27, 16), 256, 0, stream>>>(
                p.Wg + (size_t)l * DM * FF, p.Wu + (size_t)l * DM * FF,
                p.w_pa + (size_t)l * DM, p.w_pf + (size_t)l * DM, HINl, APl, HMl, ws + F_GUP_O);

            gk_wd<<<dim3(5, 64), 256, 0, stream>>>(ws + F_GUP_O, p.Wd + (size_t)l * FF * DM, DPl);
        }
        gk_logits<<<dim3(128, 6), 256, 0, stream>>>(
            p.Wlm, p.w_pof + (size_t)5 * DM, p.w_fin,
            ws + F_HM_O + (size_t)5 * DM, ws + F_DP_O + (size_t)5 * DM, ws + F_LGP_O);
        gk_amax1<<<128, 256, 0, stream>>>(ws + F_LGP_O, ws + F_AMV_O, ws + F_AMI_O);
        gk_amax2<<<1, 128, 0, stream>>>(ws + F_AMV_O, ws + F_AMI_O, p.tok);
    }
}

// Round 7
// 579.141 us; speedup vs baseline: 2.6889x; 2.6889x over previous
//
#include <hip/hip_runtime.h>
#include <hip/hip_fp16.h>
#include <cmath>

#define LNUM 6
#define DM   1152
#define DHEAD 256
#define NH   4
#define FF   6912
#define VOC  65536
#define HIST 4095
#define SEQ  4096
#define EPSV 1e-6f

// ---- ws float offsets ----
#define QKV_O 0            // [6][1536]   zeroed
#define AP_O  9216         // [6][1152]   zeroed
#define DP_O  16128        // [6][1152]   zeroed
#define GU_O  23040        // [6][13824]  zeroed
#define LG_O  105984       // [65536]     zeroed
#define ZEND  171520
#define POP_O 171520       // [128][1024]
#define SPS_O 302592       // [128][4]
#define HIN_O 303104       // [6][1152]
#define HM_O  310016       // [6][1152]
#define AMV_O 316928       // [256]
#define AMI_O 317184       // [256]

__device__ __forceinline__ float block_sum256(float v, float* red4) {
#pragma unroll
    for (int off = 32; off; off >>= 1) v += __shfl_xor(v, off);
    int t = threadIdx.x;
    if ((t & 63) == 0) red4[t >> 6] = v;
    __syncthreads();
    float r = red4[0] + red4[1] + red4[2] + red4[3];
    __syncthreads();
    return r;
}

// ---------------- cache copies (round-2 proven) ----------------
__global__ __launch_bounds__(256) void gk_copy(const float* __restrict__ kc,
                                               const float* __restrict__ vc,
                                               float* __restrict__ keys,
                                               float* __restrict__ vals) {
    int b = blockIdx.x;
    if (b < 24576) {
        int row = b >> 4;
        int s = ((b & 15) << 8) + threadIdx.x;
        if (s < HIST) keys[(size_t)row * SEQ + s] = kc[(size_t)row * HIST + s];
    } else {
        int r = (b - 24576) * 4 + (threadIdx.x >> 6);
        int d4 = threadIdx.x & 63;
        if (r < LNUM * HIST) {
            int l = r / HIST, sI = r - l * HIST;
            ((float4*)(vals + ((size_t)l * SEQ + sI) * DHEAD))[d4] =
                ((const float4*)(vc + (size_t)r * DHEAD))[d4];
        }
    }
}

// ---------------- qkv: prefix + float4 GEMV, grid(6,18) ----------------
__global__ __launch_bounds__(256) void gk_qkv(
    const float* __restrict__ Wq, const float* __restrict__ Wk, const float* __restrict__ Wv,
    const float* __restrict__ w_in, const float* __restrict__ w_pof_prev,
    const float* __restrict__ hprev, const float* __restrict__ dprev,
    const int* __restrict__ ids, const int* __restrict__ tbl,
    const float* __restrict__ escale, const float* __restrict__ ezp,
    float* __restrict__ hin_out, float* __restrict__ qkv_out, int has_prev) {
    __shared__ float xv[DM];
    __shared__ float red4[4];
    __shared__ float4 qred[256];
    int t = threadIdx.x;
    if (has_prev) {
        float ss = 0.f;
        for (int i = t; i < DM; i += 256) { float d = dprev[i]; ss += d * d; }
        ss = block_sum256(ss, red4);
        float inv = 1.f / sqrtf(ss / DM + EPSV);
        for (int i = t; i < DM; i += 256)
            xv[i] = hprev[i] + w_pof_prev[i] * dprev[i] * inv;
    } else {
        int tok = ids[0];
        float sc = escale[tok], z = ezp[tok];
        const int* row = tbl + (size_t)tok * DM;
        for (int i = t; i < DM; i += 256) xv[i] = (float)row[i] * sc + z;
    }
    __syncthreads();
    if (blockIdx.x == 0 && blockIdx.y == 0)
        for (int i = t; i < DM; i += 256) hin_out[i] = xv[i];
    float ss = 0.f;
    for (int i = t; i < DM; i += 256) { float v = xv[i]; ss += v * v; }
    ss = block_sum256(ss, red4);
    float inv = 1.f / sqrtf(ss / DM + EPSV);
    for (int i = t; i < DM; i += 256) xv[i] = w_in[i] * xv[i] * inv;
    __syncthreads();

    int f4c = t & 63, ks = t >> 6;
    int jf = blockIdx.x * 64 + f4c;          // 0..383 (f4 col)
    const float4* W4; int jj4, ncol4;
    if (jf < 256)      { W4 = (const float4*)Wq; jj4 = jf;       ncol4 = 256; }
    else if (jf < 320) { W4 = (const float4*)Wk; jj4 = jf - 256; ncol4 = 64; }
    else               { W4 = (const float4*)Wv; jj4 = jf - 320; ncol4 = 64; }
    int i0 = blockIdx.y * 64 + ks * 16;
    float4 w[16];
#pragma unroll
    for (int r = 0; r < 16; ++r) w[r] = W4[(size_t)(i0 + r) * ncol4 + jj4];
    float4 acc = {0, 0, 0, 0};
#pragma unroll
    for (int r = 0; r < 16; ++r) {
        float xs = xv[i0 + r];
        acc.x += xs * w[r].x; acc.y += xs * w[r].y;
        acc.z += xs * w[r].z; acc.w += xs * w[r].w;
    }
    qred[t] = acc;
    __syncthreads();
    if (ks == 0) {
        float4 a = qred[f4c], b = qred[64 + f4c], c = qred[128 + f4c], d = qred[192 + f4c];
        atomicAdd(&qkv_out[4 * jf + 0], a.x + b.x + c.x + d.x);
        atomicAdd(&qkv_out[4 * jf + 1], a.y + b.y + c.y + d.y);
        atomicAdd(&qkv_out[4 * jf + 2], a.z + b.z + c.z + d.z);
        atomicAdd(&qkv_out[4 * jf + 3], a.w + b.w + c.w + d.w);
    }
}

// ---------------- fused attention (round-2 proven) ----------------
__global__ __launch_bounds__(256) void gk_attn(
    const float* __restrict__ qkv, const float* __restrict__ w_qn,
    const float* __restrict__ w_kn, const int* __restrict__ attn_flag,
    float* __restrict__ keys_l, float* __restrict__ vals_l,
    float* __restrict__ po_part, float* __restrict__ sum_part, float rope_base) {
    __shared__ float lq[NH * DHEAD];
    __shared__ float lqf[NH * DHEAD];
    __shared__ float lkn[DHEAD];
    __shared__ float lkf[DHEAD];
    __shared__ float lv[DHEAD];
    __shared__ float lp[NH * 32];
    __shared__ float red4[4];
    int t = threadIdx.x;
    int s0 = blockIdx.x * 32;
    bool last = (blockIdx.x == gridDim.x - 1);

    int jm = t & 127;
    float theta = powf(rope_base, -(float)(2 * jm) / 256.f);
    float ang = 4095.f * theta;
    float c = __half2float(__float2half(cosf(ang)));
    float s = __half2float(__float2half(sinf(ang)));

    for (int h = 0; h < NH; ++h) lq[h * 256 + t] = qkv[h * 256 + t];
    lkn[t] = qkv[1024 + t];
    lv[t]  = qkv[1280 + t];
    __syncthreads();
    for (int h = 0; h < NH; ++h) {
        float v = lq[h * 256 + t];
        float ss = block_sum256(v * v, red4);
        float inv = 1.f / sqrtf(ss / 256.f + EPSV);
        float qn = w_qn[t] * v * inv;
        lq[h * 256 + t] = qn;
        __syncthreads();
        float partner = (t < 128) ? -lq[h * 256 + t + 128] : lq[h * 256 + t - 128];
        lqf[h * 256 + t] = qn * c + partner * s;
    }
    {
        float v = lkn[t];
        float ss = block_sum256(v * v, red4);
        float inv = 1.f / sqrtf(ss / 256.f + EPSV);
        float kn = w_kn[t] * v * inv;
        lkn[t] = kn;
        __syncthreads();
        float partner = (t < 128) ? -lkn[t + 128] : lkn[t - 128];
        lkf[t] = kn * c + partner * s;
    }
    __syncthreads();
    if (last) {
        keys_l[(size_t)t * SEQ + (SEQ - 1)] = lkf[t];
        vals_l[(size_t)(SEQ - 1) * DHEAD + t] = lv[t];
    }
    int sl = t & 31, dc = t >> 5;
    int sg = s0 + sl;
    bool self = last && (sl == 31);
    float a0 = 0, a1 = 0, a2 = 0, a3 = 0;
#pragma unroll 4
    for (int dd = 0; dd < 32; ++dd) {
        int d = dc * 32 + dd;
        float kv = self ? lkf[d] : keys_l[(size_t)d * SEQ + sg];
        a0 += lqf[0 * 256 + d] * kv;
        a1 += lqf[1 * 256 + d] * kv;
        a2 += lqf[2 * 256 + d] * kv;
        a3 += lqf[3 * 256 + d] * kv;
    }
    __syncthreads();
    lq[0 * 256 + t] = a0; lq[1 * 256 + t] = a1; lq[2 * 256 + t] = a2; lq[3 * 256 + t] = a3;
    __syncthreads();
    if (t < 32) {
        int af = attn_flag[0];
        float mk = (s0 + t > 0) ? -128.f * (float)af : 0.f;
        for (int h = 0; h < NH; ++h) {
            float sc_ = 0.f;
#pragma unroll
            for (int d8 = 0; d8 < 8; ++d8) sc_ += lq[h * 256 + d8 * 32 + t];
            lp[h * 32 + t] = expf(sc_ + mk);
        }
    }
    __syncthreads();
    if (t < NH) {
        float su = 0.f;
        for (int i = 0; i < 32; ++i) su += lp[t * 32 + i];
        sum_part[blockIdx.x * NH + t] = su;
    }
    float p0 = 0, p1 = 0, p2 = 0, p3 = 0;
#pragma unroll 4
    for (int ss_ = 0; ss_ < 32; ++ss_) {
        float v = (last && ss_ == 31) ? lv[t] : vals_l[(size_t)(s0 + ss_) * DHEAD + t];
        p0 += lp[0 * 32 + ss_] * v;
        p1 += lp[1 * 32 + ss_] * v;
        p2 += lp[2 * 32 + ss_] * v;
        p3 += lp[3 * 32 + ss_] * v;
    }
    float* po = po_part + (size_t)blockIdx.x * NH * DHEAD;
    po[0 * 256 + t] = p0; po[1 * 256 + t] = p1; po[2 * 256 + t] = p2; po[3 * 256 + t] = p3;
}

// ---------------- wo (round-2 proven), grid(5,16) ----------------
__global__ __launch_bounds__(256) void gk_wo(
    const float* __restrict__ po_part, const float* __restrict__ sum_part,
    const float* __restrict__ Wo_l, float* __restrict__ aproj) {
    __shared__ float x[64];
    __shared__ float hinv[NH];
    __shared__ float red4[4];
    int t = threadIdx.x;
    for (int h = 0; h < NH; ++h) {
        float v = (t < 128) ? sum_part[t * NH + h] : 0.f;
        float tot = block_sum256(v, red4);
        if (t == 0) hinv[h] = 1.f / tot;
    }
    __syncthreads();
    int i0 = blockIdx.y * 64;
    if (t < 64) {
        float a = 0.f;
#pragma unroll 8
        for (int b = 0; b < 128; ++b) a += po_part[(size_t)b * 1024 + i0 + t];
        x[t] = a * hinv[(i0 + t) >> 8];
    }
    __syncthreads();
    int j = blockIdx.x * 256 + t;
    if (j < DM) {
        float acc = 0.f;
#pragma unroll 4
        for (int ii = 0; ii < 64; ++ii)
            acc += x[ii] * Wo_l[(size_t)(i0 + ii) * DM + j];
        atomicAdd(&aproj[j], acc);
    }
}

// ---------------- gu: prefix + float4 GEMV, grid(54,18) ----------------
__global__ __launch_bounds__(256) void gk_gu(
    const float* __restrict__ Wg_l, const float* __restrict__ Wu_l,
    const float* __restrict__ w_pa, const float* __restrict__ w_pf,
    const float* __restrict__ hin, const float* __restrict__ aproj,
    float* __restrict__ hmid_out, float* __restrict__ gu_out) {
    __shared__ float xv[DM];
    __shared__ float red4[4];
    __shared__ float4 gred[256];
    int t = threadIdx.x;
    float ss = 0.f;
    for (int i = t; i < DM; i += 256) { float a = aproj[i]; ss += a * a; }
    ss = block_sum256(ss, red4);
    float inv = 1.f / sqrtf(ss / DM + EPSV);
    for (int i = t; i < DM; i += 256) xv[i] = hin[i] + w_pa[i] * aproj[i] * inv;
    __syncthreads();
    if (blockIdx.x == 0 && blockIdx.y == 0)
        for (int i = t; i < DM; i += 256) hmid_out[i] = xv[i];
    float s2 = 0.f;
    for (int i = t; i < DM; i += 256) { float v = xv[i]; s2 += v * v; }
    s2 = block_sum256(s2, red4);
    float inv2 = 1.f / sqrtf(s2 / DM + EPSV);
    for (int i = t; i < DM; i += 256) xv[i] = w_pf[i] * xv[i] * inv2;
    __syncthreads();

    int f4c = t & 63, ks = t >> 6;
    int cgi = blockIdx.x;
    bool isU = cgi >= 27;
    int cg = isU ? cgi - 27 : cgi;
    const float4* W4 = (const float4*)(isU ? Wu_l : Wg_l);
    int colf4 = cg * 64 + f4c;               // 0..1727
    int i0 = blockIdx.y * 64 + ks * 16;
    float4 w[16];
#pragma unroll
    for (int r = 0; r < 16; ++r) w[r] = W4[(size_t)(i0 + r) * 1728 + colf4];
    float4 acc = {0, 0, 0, 0};
#pragma unroll
    for (int r = 0; r < 16; ++r) {
        float xs = xv[i0 + r];
        acc.x += xs * w[r].x; acc.y += xs * w[r].y;
        acc.z += xs * w[r].z; acc.w += xs * w[r].w;
    }
    gred[t] = acc;
    __syncthreads();
    if (ks == 0) {
        float4 a = gred[f4c], b = gred[64 + f4c], c = gred[128 + f4c], d = gred[192 + f4c];
        float* dst = gu_out + (isU ? FF : 0) + 4 * colf4;
        atomicAdd(dst + 0, a.x + b.x + c.x + d.x);
        atomicAdd(dst + 1, a.y + b.y + c.y + d.y);
        atomicAdd(dst + 2, a.z + b.z + c.z + d.z);
        atomicAdd(dst + 3, a.w + b.w + c.w + d.w);
    }
}

// ---------------- wd: gelu prefix + float4 GEMV, grid(5,108) ----------------
__global__ __launch_bounds__(256) void gk_wd(const float* __restrict__ gu,
                                             const float* __restrict__ Wd_l,
                                             float* __restrict__ dproj) {
    __shared__ float m[64];
    __shared__ float4 wred[256];
    int t = threadIdx.x;
    int i0 = blockIdx.y * 64;
    if (t < 64) {
        float g = gu[i0 + t], u = gu[FF + i0 + t];
        float gl = 0.5f * g * (1.f + tanhf(0.7978845608028654f * (g + 0.044715f * g * g * g)));
        m[t] = gl * u;
    }
    __syncthreads();
    int f4c = t & 63, ks = t >> 6;
    int col4 = blockIdx.x * 64 + f4c;        // 0..319, valid < 288
    float4 acc = {0, 0, 0, 0};
    if (col4 < 288) {
        const float4* W4 = (const float4*)Wd_l;
        float4 w[16];
#pragma unroll
        for (int r = 0; r < 16; ++r) w[r] = W4[(size_t)(i0 + ks * 16 + r) * 288 + col4];
#pragma unroll
        for (int r = 0; r < 16; ++r) {
            float xs = m[ks * 16 + r];
            acc.x += xs * w[r].x; acc.y += xs * w[r].y;
            acc.z += xs * w[r].z; acc.w += xs * w[r].w;
        }
    }
    wred[t] = acc;
    __syncthreads();
    if (ks == 0 && col4 < 288) {
        float4 a = wred[f4c], b = wred[64 + f4c], c = wred[128 + f4c], d = wred[192 + f4c];
        atomicAdd(&dproj[4 * col4 + 0], a.x + b.x + c.x + d.x);
        atomicAdd(&dproj[4 * col4 + 1], a.y + b.y + c.y + d.y);
        atomicAdd(&dproj[4 * col4 + 2], a.z + b.z + c.z + d.z);
        atomicAdd(&dproj[4 * col4 + 3], a.w + b.w + c.w + d.w);
    }
}

// ---------------- logits: prefix + float4 GEMV, grid(256,18) ----------------
__global__ __launch_bounds__(256) void gk_logits(
    const float* __restrict__ W_lm, const float* __restrict__ w_pof5,
    const float* __restrict__ w_fin, const float* __restrict__ hmid5,
    const float* __restrict__ dproj5, float* __restrict__ lg) {
    __shared__ float xv[DM];
    __shared__ float red4[4];
    __shared__ float4 lred[256];
    int t = threadIdx.x;
    float ss = 0.f;
    for (int i = t; i < DM; i += 256) { float d = dproj5[i]; ss += d * d; }
    ss = block_sum256(ss, red4);
    float inv = 1.f / sqrtf(ss / DM + EPSV);
    for (int i = t; i < DM; i += 256) xv[i] = hmid5[i] + w_pof5[i] * dproj5[i] * inv;
    __syncthreads();
    float s2 = 0.f;
    for (int i = t; i < DM; i += 256) { float v = xv[i]; s2 += v * v; }
    s2 = block_sum256(s2, red4);
    float inv2 = 1.f / sqrtf(s2 / DM + EPSV);
    for (int i = t; i < DM; i += 256) xv[i] = w_fin[i] * xv[i] * inv2;
    __syncthreads();

    int f4c = t & 63, ks = t >> 6;
    int colf4 = blockIdx.x * 64 + f4c;       // 0..16383
    int i0 = blockIdx.y * 64 + ks * 16;
    const float4* W4 = (const float4*)W_lm;
    float4 w[16];
#pragma unroll
    for (int r = 0; r < 16; ++r) w[r] = W4[(size_t)(i0 + r) * 16384 + colf4];
    float4 acc = {0, 0, 0, 0};
#pragma unroll
    for (int r = 0; r < 16; ++r) {
        float xs = xv[i0 + r];
        acc.x += xs * w[r].x; acc.y += xs * w[r].y;
        acc.z += xs * w[r].z; acc.w += xs * w[r].w;
    }
    lred[t] = acc;
    __syncthreads();
    if (ks == 0) {
        float4 a = lred[f4c], b = lred[64 + f4c], c = lred[128 + f4c], d = lred[192 + f4c];
        atomicAdd(&lg[4 * colf4 + 0], a.x + b.x + c.x + d.x);
        atomicAdd(&lg[4 * colf4 + 1], a.y + b.y + c.y + d.y);
        atomicAdd(&lg[4 * colf4 + 2], a.z + b.z + c.z + d.z);
        atomicAdd(&lg[4 * colf4 + 3], a.w + b.w + c.w + d.w);
    }
}

// ---------------- argmax ----------------
__global__ __launch_bounds__(256) void gk_amax1(const float* __restrict__ lg,
                                                float* __restrict__ pv, float* __restrict__ pi) {
    __shared__ float rv[256];
    __shared__ int ri[256];
    int t = threadIdx.x;
    int c = blockIdx.x * 256 + t;
    rv[t] = lg[c]; ri[t] = c;
    __syncthreads();
    for (int off = 128; off > 0; off >>= 1) {
        if (t < off) {
            float ov = rv[t + off]; int oi = ri[t + off];
            if (ov > rv[t] || (ov == rv[t] && oi < ri[t])) { rv[t] = ov; ri[t] = oi; }
        }
        __syncthreads();
    }
    if (t == 0) { pv[blockIdx.x] = rv[0]; pi[blockIdx.x] = (float)ri[0]; }
}

__global__ __launch_bounds__(256) void gk_amax2(const float* __restrict__ pv,
                                                const float* __restrict__ pi,
                                                float* __restrict__ tok_out) {
    __shared__ float rv[256];
    __shared__ int ri[256];
    int t = threadIdx.x;
    rv[t] = pv[t]; ri[t] = (int)pi[t];
    __syncthreads();
    for (int off = 128; off > 0; off >>= 1) {
        if (t < off) {
            float ov = rv[t + off]; int oi = ri[t + off];
            if (ov > rv[t] || (ov == rv[t] && oi < ri[t])) { rv[t] = ov; ri[t] = oi; }
        }
        __syncthreads();
    }
    if (t == 0) tok_out[0] = (float)ri[0];
}

// ==================== host launcher ====================
extern "C" void kernel_launch(void* const* d_in, const int* in_sizes, int n_in,
                              void* d_out, int out_size, void* d_ws, size_t ws_size,
                              hipStream_t stream) {
    const int*   ids   = (const int*)d_in[0];
    const int*   aflag = (const int*)d_in[1];
    const float* kc    = (const float*)d_in[2];
    const float* vc    = (const float*)d_in[3];
    const int*   tbl   = (const int*)d_in[4];
    const float* esc   = (const float*)d_in[5];
    const float* ezp   = (const float*)d_in[6];
    const float* w_in  = (const float*)d_in[7];
    const float* w_qn  = (const float*)d_in[8];
    const float* w_kn  = (const float*)d_in[9];
    const float* Wq    = (const float*)d_in[10];
    const float* Wk    = (const float*)d_in[11];
    const float* Wv    = (const float*)d_in[12];
    const float* Wo    = (const float*)d_in[13];
    const float* w_pa  = (const float*)d_in[14];
    const float* w_pf  = (const float*)d_in[15];
    const float* w_pof = (const float*)d_in[16];
    const float* Wg    = (const float*)d_in[17];
    const float* Wu    = (const float*)d_in[18];
    const float* Wd    = (const float*)d_in[19];
    const float* w_fin = (const float*)d_in[20];
    const float* Wlm   = (const float*)d_in[21];

    float* keys = (float*)d_out;
    float* vals = keys + (size_t)LNUM * DHEAD * SEQ;
    float* tok  = vals + (size_t)LNUM * SEQ * DHEAD;
    float* ws = (float*)d_ws;

    hipMemsetAsync(ws, 0, ZEND * sizeof(float), stream);
    gk_copy<<<24576 + 6144, 256, 0, stream>>>(kc, vc, keys, vals);

    for (int l = 0; l < LNUM; ++l) {
        float* QKVl = ws + QKV_O + (size_t)l * 1536;
        float* APl  = ws + AP_O + (size_t)l * DM;
        float* DPl  = ws + DP_O + (size_t)l * DM;
        float* GUl  = ws + GU_O + (size_t)l * 2 * FF;
        float* HINl = ws + HIN_O + (size_t)l * DM;
        float* HMl  = ws + HM_O + (size_t)l * DM;
        float* keys_l = keys + (size_t)l * DHEAD * SEQ;
        float* vals_l = vals + (size_t)l * SEQ * DHEAD;

        gk_qkv<<<dim3(6, 18), 256, 0, stream>>>(
            Wq + (size_t)l * DM * 1024, Wk + (size_t)l * DM * 256,
            Wv + (size_t)l * DM * 256, w_in + (size_t)l * DM,
            w_pof + (size_t)(l ? l - 1 : 0) * DM,
            (l ? ws + HM_O + (size_t)(l - 1) * DM : nullptr),
            (l ? ws + DP_O + (size_t)(l - 1) * DM : nullptr),
            ids, tbl, esc, ezp, HINl, QKVl, (l > 0) ? 1 : 0);

        gk_attn<<<128, 256, 0, stream>>>(
            QKVl, w_qn + (size_t)l * DHEAD, w_kn + (size_t)l * DHEAD,
            aflag, keys_l, vals_l, ws + POP_O, ws + SPS_O,
            ((l % 6) != 5) ? 1000000.0f : 10000.0f);

        gk_wo<<<dim3(5, 16), 256, 0, stream>>>(
            ws + POP_O, ws + SPS_O, Wo + (size_t)l * 1024 * DM, APl);

        gk_gu<<<dim3(54, 18), 256, 0, stream>>>(
            Wg + (size_t)l * DM * FF, Wu + (size_t)l * DM * FF,
            w_pa + (size_t)l * DM, w_pf + (size_t)l * DM, HINl, APl, HMl, GUl);

        gk_wd<<<dim3(5, 108), 256, 0, stream>>>(GUl, Wd + (size_t)l * FF * DM, DPl);
    }

    gk_logits<<<dim3(256, 18), 256, 0, stream>>>(
        Wlm, w_pof + (size_t)5 * DM, w_fin,
        ws + HM_O + (size_t)5 * DM, ws + DP_O + (size_t)5 * DM, ws + LG_O);
    gk_amax1<<<256, 256, 0, stream>>>(ws + LG_O, ws + AMV_O, ws + AMI_O);
    gk_amax2<<<1, 256, 0, stream>>>(ws + AMV_O, ws + AMI_O, tok);
}